// Round 5
// baseline (455.754 us; speedup 1.0000x reference)
//
#include <hip/hip_runtime.h>
#include <math.h>

#define CAP2   511           // max in-edges of target node (expected ~16)
#define CAPS1  512           // max 1-hop node set size (<= NBLK!)
#define CAP1   65536         // max edges into S1 nodes (expected ~300)
#define CAPN   512           // per-node in-edge cap in layer-1 phase
#define NBLK   512           // persistent grid: 2 blocks/CU needed, 4/CU capacity

// header (first 256 B of ws, zeroed by hipMemsetAsync every call):
// [0]=cnt2  [2]=n_s1  [3]=nE2  [4]=ea_sum(float bits)  [8]=cnt1
// [32]=barrier count  [33]=barrier generation

__device__ __forceinline__ void grid_sync(int* cnt, int* gen) {
    __syncthreads();
    if (threadIdx.x == 0) {
        __threadfence();   // agent-scope fence: flush this block's writes
        int g = __hip_atomic_load(gen, __ATOMIC_RELAXED, __HIP_MEMORY_SCOPE_AGENT);
        int prev = __hip_atomic_fetch_add(cnt, 1, __ATOMIC_ACQ_REL, __HIP_MEMORY_SCOPE_AGENT);
        if (prev == NBLK - 1) {
            __hip_atomic_store(cnt, 0, __ATOMIC_RELAXED, __HIP_MEMORY_SCOPE_AGENT);
            __hip_atomic_store(gen, g + 1, __ATOMIC_RELEASE, __HIP_MEMORY_SCOPE_AGENT);
        } else {
            while (__hip_atomic_load(gen, __ATOMIC_ACQUIRE, __HIP_MEMORY_SCOPE_AGENT) == g)
                __builtin_amdgcn_s_sleep(1);
        }
        __threadfence();
    }
    __syncthreads();
}

__global__ __launch_bounds__(256, 4)
void k_mega(const float* __restrict__ x, const int* __restrict__ ei,
            const float* __restrict__ ea, const int* __restrict__ tptr,
            const float* __restrict__ Wl1, const float* __restrict__ bl1,
            const float* __restrict__ Wr1, const float* __restrict__ br1,
            const float* __restrict__ We1, const float* __restrict__ att1,
            const float* __restrict__ b1,
            const float* __restrict__ Wl2, const float* __restrict__ bl2,
            const float* __restrict__ Wr2, const float* __restrict__ br2,
            const float* __restrict__ We2, const float* __restrict__ att2,
            const float* __restrict__ b2,
            const float* __restrict__ Wf, const float* __restrict__ bf,
            int E,
            int* hdr, float* partials, int* S1nodes,
            int* L2_src, int* L2_s1idx, float* L2_ea,
            int* L1_src, int* L1_dst, float* L1_ea,
            float* xl2, float* xr2, float* out) {
    int tid = threadIdx.x, lane = tid & 63, wq = tid >> 6;
    int bid = blockIdx.x;
    int gid = bid * 256 + tid;
    const int gstride = NBLK * 256;
    int* bar_cnt = &hdr[32];
    int* bar_gen = &hdr[33];

    __shared__ float wsum[4];
    __shared__ int   s1[CAPS1];
    __shared__ int   esrc[CAPN + 1];
    __shared__ float eea[CAPN + 1];
    __shared__ float xsA[CAPN + 1], xsB[CAPN + 1];
    __shared__ float scores[CAPN + 1];
    __shared__ float part[4][64];
    __shared__ float hrow[64];
    __shared__ float m_sh, d_sh;
    __shared__ int   scnt;

    // ---------------- phase 1: scanA (target in-edges + ea partial sums) ----
    {
        int t = tptr[0];
        float local = 0.f;
        const int4*   dst4 = (const int4*)(ei + E);
        const float4* ea4  = (const float4*)ea;
        int E4 = E >> 2;
        for (int e4 = gid; e4 < E4; e4 += gstride) {
            int4 d = dst4[e4];
            float4 a = ea4[e4];
            local += a.x + a.y + a.z + a.w;
            int eb = e4 * 4;
            if (d.x == t) { int p = atomicAdd(&hdr[0], 1); if (p < CAP2) { L2_src[p] = ei[eb];     L2_ea[p] = a.x; } }
            if (d.y == t) { int p = atomicAdd(&hdr[0], 1); if (p < CAP2) { L2_src[p] = ei[eb + 1]; L2_ea[p] = a.y; } }
            if (d.z == t) { int p = atomicAdd(&hdr[0], 1); if (p < CAP2) { L2_src[p] = ei[eb + 2]; L2_ea[p] = a.z; } }
            if (d.w == t) { int p = atomicAdd(&hdr[0], 1); if (p < CAP2) { L2_src[p] = ei[eb + 3]; L2_ea[p] = a.w; } }
        }
        if (gid == 0) {                  // tail (E % 4)
            for (int e = E4 * 4; e < E; e++) {
                float a = ea[e];
                local += a;
                if (ei[E + e] == t) { int p = atomicAdd(&hdr[0], 1); if (p < CAP2) { L2_src[p] = ei[e]; L2_ea[p] = a; } }
            }
        }
        for (int o = 32; o >= 1; o >>= 1) local += __shfl_xor(local, o, 64);
        if (lane == 0) wsum[wq] = local;
        __syncthreads();
        if (tid == 0) partials[bid] = wsum[0] + wsum[1] + wsum[2] + wsum[3];
    }
    grid_sync(bar_cnt, bar_gen);

    // ---------------- phase 2: reduce partials + build S1 (block 0) ---------
    if (bid == 0) {
        float local = partials[tid] + partials[tid + 256];
        for (int o = 32; o >= 1; o >>= 1) local += __shfl_xor(local, o, 64);
        if (lane == 0) wsum[wq] = local;
        __syncthreads();
        if (tid == 0) {
            ((float*)hdr)[4] = wsum[0] + wsum[1] + wsum[2] + wsum[3];
            int t = tptr[0];
            s1[0] = t;
            int n = 1;
            int c2 = hdr[0]; if (c2 > CAP2) c2 = CAP2;
            for (int k = 0; k < c2; k++) {
                int v = L2_src[k];
                int idx = -1;
                for (int j = 0; j < n; j++) if (s1[j] == v) { idx = j; break; }
                if (idx < 0) { idx = n; s1[n] = v; n++; }
                L2_s1idx[k] = idx;
            }
            hdr[2] = n;
            hdr[3] = c2;
            for (int j = 0; j < n; j++) S1nodes[j] = s1[j];
        }
    }
    grid_sync(bar_cnt, bar_gen);

    int n_s1 = hdr[2];
    float eam = ((const float*)hdr)[4] / (float)E;

    // ---------------- phase 3: scanC (edges into S1; dst re-read is L2-hot) -
    {
        for (int j = tid; j < n_s1; j += 256) s1[j] = S1nodes[j];
        __syncthreads();
        const int4* dst4 = (const int4*)(ei + E);
        int E4 = E >> 2;
        for (int e4 = gid; e4 < E4; e4 += gstride) {
            int4 d = dst4[e4];
            int eb = e4 * 4;
            int dd[4] = {d.x, d.y, d.z, d.w};
            #pragma unroll
            for (int q = 0; q < 4; q++) {
                int idx = -1;
                for (int j = 0; j < n_s1; j++) if (s1[j] == dd[q]) { idx = j; break; }
                if (idx >= 0) {
                    int p = atomicAdd(&hdr[8], 1);
                    if (p < CAP1) { L1_src[p] = ei[eb + q]; L1_dst[p] = idx; L1_ea[p] = ea[eb + q]; }
                }
            }
        }
        if (gid == 0) {
            for (int e = E4 * 4; e < E; e++) {
                int dv = ei[E + e];
                int idx = -1;
                for (int j = 0; j < n_s1; j++) if (s1[j] == dv) { idx = j; break; }
                if (idx >= 0) {
                    int p = atomicAdd(&hdr[8], 1);
                    if (p < CAP1) { L1_src[p] = ei[e]; L1_dst[p] = idx; L1_ea[p] = ea[e]; }
                }
            }
        }
    }
    grid_sync(bar_cnt, bar_gen);

    // ---------------- phase 4: layer 1 + fused layer-2 transforms -----------
    if (bid < n_s1) {
        int v = S1nodes[bid];
        if (tid == 0) scnt = 0;
        __syncthreads();

        int c1 = hdr[8]; if (c1 > CAP1) c1 = CAP1;
        for (int k = tid; k < c1; k += 256) {
            if (L1_dst[k] == bid) {
                int p = atomicAdd(&scnt, 1);
                if (p < CAPN) { esrc[p] = L1_src[k]; eea[p] = L1_ea[k]; }
            }
        }
        __syncthreads();
        int nE = scnt; if (nE > CAPN) nE = CAPN;
        if (tid == 0) { esrc[nE] = v; eea[nE] = eam; }   // self-loop
        __syncthreads();
        nE += 1;

        const float2* x2 = (const float2*)x;
        for (int j = tid; j < nE; j += 256) {            // parallel x gather
            float2 xv = x2[esrc[j]];
            xsA[j] = xv.x; xsB[j] = xv.y;
        }
        __syncthreads();

        float wl0 = Wl1[lane], wl1w = Wl1[64 + lane], bl = bl1[lane];
        float we = We1[lane], at = att1[lane];
        float2 xv = x2[v];
        float xr = xv.x * Wr1[lane] + xv.y * Wr1[64 + lane] + br1[lane];

        for (int k = wq; k < nE; k += 4) {               // scores
            float xl = xsA[k] * wl0 + xsB[k] * wl1w + bl;
            float ev = xl + xr + eea[k] * we;
            ev = ev > 0.f ? ev : 0.2f * ev;
            float p = ev * at;
            for (int o = 32; o >= 1; o >>= 1) p += __shfl_xor(p, o, 64);
            if (lane == 0) scores[k] = p;
        }
        __syncthreads();

        if (wq == 0) {                                   // softmax stats
            float m = -3.4e38f;
            for (int k = lane; k < nE; k += 64) m = fmaxf(m, scores[k]);
            for (int o = 32; o >= 1; o >>= 1) m = fmaxf(m, __shfl_xor(m, o, 64));
            float d = 0.f;
            for (int k = lane; k < nE; k += 64) d += expf(scores[k] - m);
            for (int o = 32; o >= 1; o >>= 1) d += __shfl_xor(d, o, 64);
            if (lane == 0) { m_sh = m; d_sh = d; }
        }
        __syncthreads();
        float m = m_sh, dinv = 1.f / d_sh;

        float acc = 0.f;                                 // weighted sum
        for (int k = wq; k < nE; k += 4) {
            float xl = xsA[k] * wl0 + xsB[k] * wl1w + bl;
            acc += expf(scores[k] - m) * dinv * xl;
        }
        part[wq][lane] = acc;
        __syncthreads();
        if (tid < 64) {
            float h = part[0][lane] + part[1][lane] + part[2][lane] + part[3][lane] + b1[lane];
            hrow[lane] = h > 0.f ? h : 0.f;
        }
        __syncthreads();

        // fused: xl2[bid] = Wl2^T hrow + bl2 (k-split across waves)
        float p = 0.f;
        int k0 = 16 * wq;
        for (int k = k0; k < k0 + 16; k++) p += hrow[k] * Wl2[k * 64 + lane];
        part[wq][lane] = p;
        __syncthreads();
        if (tid < 64)
            xl2[bid * 64 + lane] = part[0][lane] + part[1][lane] + part[2][lane] + part[3][lane] + bl2[lane];

        if (bid == 0) {                                  // target transform
            __syncthreads();
            float p2 = 0.f;
            for (int k = k0; k < k0 + 16; k++) p2 += hrow[k] * Wr2[k * 64 + lane];
            part[wq][lane] = p2;
            __syncthreads();
            if (tid < 64)
                xr2[lane] = part[0][lane] + part[1][lane] + part[2][lane] + part[3][lane] + br2[lane];
        }
    }
    grid_sync(bar_cnt, bar_gen);

    // ---------------- phase 5: target layer-2 softmax + head (block 0) ------
    if (bid == 0) {
        int nE2 = hdr[3];
        if (tid < 64) {
            float we = We2[lane], at = att2[lane], xr = xr2[lane];
            for (int j = 0; j <= nE2; j++) {
                int   idx = (j < nE2) ? L2_s1idx[j] : 0;
                float eav = (j < nE2) ? L2_ea[j]    : eam;
                float ev = xl2[idx * 64 + lane] + xr + eav * we;
                ev = ev > 0.f ? ev : 0.2f * ev;
                float p = ev * at;
                for (int o = 32; o >= 1; o >>= 1) p += __shfl_xor(p, o, 64);
                if (lane == 0) scores[j] = p;
            }
            int tot = nE2 + 1;
            float m = -3.4e38f;
            for (int j = lane; j < tot; j += 64) m = fmaxf(m, scores[j]);
            for (int o = 32; o >= 1; o >>= 1) m = fmaxf(m, __shfl_xor(m, o, 64));
            float d = 0.f;
            for (int j = lane; j < tot; j += 64) d += expf(scores[j] - m);
            for (int o = 32; o >= 1; o >>= 1) d += __shfl_xor(d, o, 64);

            float acc = 0.f;
            for (int j = 0; j < tot; j++) {
                int idx = (j < nE2) ? L2_s1idx[j] : 0;
                acc += expf(scores[j] - m) / d * xl2[idx * 64 + lane];
            }
            float h = acc + b2[lane];
            hrow[lane] = h > 0.f ? h : 0.f;
        }
        __syncthreads();
        if (tid < 128) {
            float r = bf[tid];
            for (int c = 0; c < 64; c++) r += hrow[c] * Wf[c * 128 + tid];
            out[tid] = r;
        }
    }
}

extern "C" void kernel_launch(void* const* d_in, const int* in_sizes, int n_in,
                              void* d_out, int out_size, void* d_ws, size_t ws_size,
                              hipStream_t stream) {
    const float* x    = (const float*)d_in[0];
    const int*   ei   = (const int*)  d_in[1];
    const float* ea   = (const float*)d_in[2];
    const int*   tptr = (const int*)  d_in[3];
    const float* Wl1  = (const float*)d_in[4];
    const float* bl1  = (const float*)d_in[5];
    const float* Wr1  = (const float*)d_in[6];
    const float* br1  = (const float*)d_in[7];
    const float* We1  = (const float*)d_in[8];
    const float* att1 = (const float*)d_in[9];
    const float* b1   = (const float*)d_in[10];
    const float* Wl2  = (const float*)d_in[11];
    const float* bl2  = (const float*)d_in[12];
    const float* Wr2  = (const float*)d_in[13];
    const float* br2  = (const float*)d_in[14];
    const float* We2  = (const float*)d_in[15];
    const float* att2 = (const float*)d_in[16];
    const float* b2   = (const float*)d_in[17];
    const float* Wf   = (const float*)d_in[18];
    const float* bf   = (const float*)d_in[19];

    int E = in_sizes[2];

    char* base = (char*)d_ws;
    int*   hdr      = (int*)base;   base += 256;   // includes barrier state
    float* partials = (float*)base; base += NBLK * sizeof(float);
    int*   S1nodes  = (int*)base;   base += CAPS1 * sizeof(int);
    int*   L2_src   = (int*)base;   base += CAP2 * sizeof(int);
    int*   L2_s1idx = (int*)base;   base += CAP2 * sizeof(int);
    float* L2_ea    = (float*)base; base += CAP2 * sizeof(float);
    int*   L1_src   = (int*)base;   base += CAP1 * sizeof(int);
    int*   L1_dst   = (int*)base;   base += CAP1 * sizeof(int);
    float* L1_ea    = (float*)base; base += CAP1 * sizeof(float);
    float* xl2      = (float*)base; base += (size_t)CAPS1 * 64 * sizeof(float);
    float* xr2      = (float*)base; base += 64 * sizeof(float);

    // Barrier counters/generation live in hdr[32..33]; ws is re-poisoned to
    // 0xAA before every timed launch, so this memset is load-bearing.
    hipMemsetAsync(hdr, 0, 256, stream);

    hipLaunchKernelGGL(k_mega, dim3(NBLK), dim3(256), 0, stream,
                       x, ei, ea, tptr,
                       Wl1, bl1, Wr1, br1, We1, att1, b1,
                       Wl2, bl2, Wr2, br2, We2, att2, b2,
                       Wf, bf, E,
                       hdr, partials, S1nodes,
                       L2_src, L2_s1idx, L2_ea,
                       L1_src, L1_dst, L1_ea,
                       xl2, xr2, (float*)d_out);
}

// Round 6
// 215.640 us; speedup vs baseline: 2.1135x; 2.1135x over previous
//
#include <hip/hip_runtime.h>
#include <math.h>

#define CAP2   511           // max in-edges of target node (expected ~16)
#define CAPS1  512           // max 1-hop node set size
#define CAP1   65536         // max edges into S1 nodes (expected ~300)
#define CAPN   512           // per-node in-edge cap in layer-1 phase
#define NBLK   256           // persistent grid: 1 block/CU — co-residency guaranteed
#define NGRP   8
#define GRPSZ  (NBLK / NGRP)

// ws layout: hdr (256 B: [0]=cnt2, [8]=cnt1) | bar (1280 B) | data arrays.
// hdr+bar are zeroed by hipMemsetAsync every call (ws is re-poisoned to 0xAA).
// Barrier: monotonic epoch counters. Group g counter at bar[32*g] (128-B
// spaced), root at bar[256], generation at bar[288].
// CRITICAL: poll RELAXED (agent-scope relaxed load = LLC access, no
// buffer_inv); a single acquire fence after exit. R5's ACQUIRE poll emitted
// buffer_inv per iteration -> L2 wiped continuously -> 367 us.

__device__ __forceinline__ void grid_sync(int* bar, int epoch) {
    __syncthreads();
    if (threadIdx.x == 0) {
        // make this block's prior writes visible at agent scope
        __builtin_amdgcn_fence(__ATOMIC_RELEASE, "agent");
        int g = blockIdx.x & (NGRP - 1);
        int prev = __hip_atomic_fetch_add(&bar[32 * g], 1,
                     __ATOMIC_ACQ_REL, __HIP_MEMORY_SCOPE_AGENT);
        if (prev == (epoch + 1) * GRPSZ - 1) {            // last of group
            int p2 = __hip_atomic_fetch_add(&bar[256], 1,
                       __ATOMIC_ACQ_REL, __HIP_MEMORY_SCOPE_AGENT);
            if (p2 == (epoch + 1) * NGRP - 1)             // last group
                __hip_atomic_store(&bar[288], epoch + 1,
                    __ATOMIC_RELEASE, __HIP_MEMORY_SCOPE_AGENT);
        }
        while (__hip_atomic_load(&bar[288], __ATOMIC_RELAXED,
                                 __HIP_MEMORY_SCOPE_AGENT) < epoch + 1)
            __builtin_amdgcn_s_sleep(2);
        __builtin_amdgcn_fence(__ATOMIC_ACQUIRE, "agent");
    }
    __syncthreads();
}

__global__ __launch_bounds__(256, 4)
void k_mega(const float* __restrict__ x, const int* __restrict__ ei,
            const float* __restrict__ ea, const int* __restrict__ tptr,
            const float* __restrict__ Wl1, const float* __restrict__ bl1,
            const float* __restrict__ Wr1, const float* __restrict__ br1,
            const float* __restrict__ We1, const float* __restrict__ att1,
            const float* __restrict__ b1,
            const float* __restrict__ Wl2, const float* __restrict__ bl2,
            const float* __restrict__ Wr2, const float* __restrict__ br2,
            const float* __restrict__ We2, const float* __restrict__ att2,
            const float* __restrict__ b2,
            const float* __restrict__ Wf, const float* __restrict__ bf,
            int E,
            int* hdr, int* bar, float* partials,
            int* L2_src, float* L2_ea,
            int* L1_src, int* L1_dst, float* L1_ea,
            float* xl2, float* out) {
    int tid = threadIdx.x, lane = tid & 63, wq = tid >> 6;
    int bid = blockIdx.x;
    int gid = bid * 256 + tid;
    const int gstride = NBLK * 256;

    __shared__ float wsum[4];
    __shared__ int   s1[CAPS1];
    __shared__ int   l2idx[CAP2];
    __shared__ int   esrc[CAPN + 1];
    __shared__ float eea[CAPN + 1];
    __shared__ float xsA[CAPN + 1], xsB[CAPN + 1];
    __shared__ float scores[CAPN + 1];
    __shared__ float part[4][64];
    __shared__ float hrow[64];
    __shared__ float xr2s[64];
    __shared__ float m_sh, d_sh, eam_sh;
    __shared__ int   n_sh, scnt;

    // ---------------- phase 1: scanA (target in-edges + ea partial sums) ----
    {
        int t = tptr[0];
        float local = 0.f;
        const int4*   dst4 = (const int4*)(ei + E);
        const float4* ea4  = (const float4*)ea;
        int E4 = E >> 2;
        for (int e4 = gid; e4 < E4; e4 += gstride) {
            int4 d = dst4[e4];
            float4 a = ea4[e4];
            local += a.x + a.y + a.z + a.w;
            int eb = e4 * 4;
            if (d.x == t) { int p = atomicAdd(&hdr[0], 1); if (p < CAP2) { L2_src[p] = ei[eb];     L2_ea[p] = a.x; } }
            if (d.y == t) { int p = atomicAdd(&hdr[0], 1); if (p < CAP2) { L2_src[p] = ei[eb + 1]; L2_ea[p] = a.y; } }
            if (d.z == t) { int p = atomicAdd(&hdr[0], 1); if (p < CAP2) { L2_src[p] = ei[eb + 2]; L2_ea[p] = a.z; } }
            if (d.w == t) { int p = atomicAdd(&hdr[0], 1); if (p < CAP2) { L2_src[p] = ei[eb + 3]; L2_ea[p] = a.w; } }
        }
        if (gid == 0) {                  // tail (E % 4)
            for (int e = E4 * 4; e < E; e++) {
                float a = ea[e];
                local += a;
                if (ei[E + e] == t) { int p = atomicAdd(&hdr[0], 1); if (p < CAP2) { L2_src[p] = ei[e]; L2_ea[p] = a; } }
            }
        }
        for (int o = 32; o >= 1; o >>= 1) local += __shfl_xor(local, o, 64);
        if (lane == 0) wsum[wq] = local;
        __syncthreads();
        if (tid == 0) partials[bid] = wsum[0] + wsum[1] + wsum[2] + wsum[3];
    }
    grid_sync(bar, 0);

    // ------- phase 2+3 (merged, all blocks redundantly): ea_sum reduce, -----
    // ------- S1 dedupe into LDS, then scanC over all edges ------------------
    int c2 = hdr[0]; if (c2 > CAP2) c2 = CAP2;
    {
        float local = partials[tid];                      // NBLK == 256
        for (int o = 32; o >= 1; o >>= 1) local += __shfl_xor(local, o, 64);
        if (lane == 0) wsum[wq] = local;
        // preload L2_src into LDS (parallel) for the serial dedupe
        for (int k = tid; k < c2; k += 256) esrc[k] = L2_src[k];
        __syncthreads();
        if (tid == 0) {
            eam_sh = (wsum[0] + wsum[1] + wsum[2] + wsum[3]) / (float)E;
            int t = tptr[0];
            s1[0] = t;
            int n = 1;
            for (int k = 0; k < c2; k++) {
                int v = esrc[k];
                int idx = -1;
                for (int j = 0; j < n; j++) if (s1[j] == v) { idx = j; break; }
                if (idx < 0) { idx = n; s1[n] = v; n++; }
                l2idx[k] = idx;
            }
            n_sh = n;
        }
        __syncthreads();
        int n_s1 = n_sh;
        const int4* dst4 = (const int4*)(ei + E);
        int E4 = E >> 2;
        for (int e4 = gid; e4 < E4; e4 += gstride) {
            int4 d = dst4[e4];
            int eb = e4 * 4;
            int dd[4] = {d.x, d.y, d.z, d.w};
            #pragma unroll
            for (int q = 0; q < 4; q++) {
                int idx = -1;
                for (int j = 0; j < n_s1; j++) if (s1[j] == dd[q]) { idx = j; break; }
                if (idx >= 0) {
                    int p = atomicAdd(&hdr[8], 1);
                    if (p < CAP1) { L1_src[p] = ei[eb + q]; L1_dst[p] = idx; L1_ea[p] = ea[eb + q]; }
                }
            }
        }
        if (gid == 0) {
            for (int e = E4 * 4; e < E; e++) {
                int dv = ei[E + e];
                int idx = -1;
                for (int j = 0; j < n_s1; j++) if (s1[j] == dv) { idx = j; break; }
                if (idx >= 0) {
                    int p = atomicAdd(&hdr[8], 1);
                    if (p < CAP1) { L1_src[p] = ei[e]; L1_dst[p] = idx; L1_ea[p] = ea[e]; }
                }
            }
        }
    }
    grid_sync(bar, 1);

    int n_s1 = n_sh;
    float eam = eam_sh;

    // ---------------- phase 4: layer 1 + fused layer-2 transforms -----------
    for (int node = bid; node < n_s1; node += NBLK) {
        int v = s1[node];
        if (tid == 0) scnt = 0;
        __syncthreads();

        int c1 = hdr[8]; if (c1 > CAP1) c1 = CAP1;
        for (int k = tid; k < c1; k += 256) {
            if (L1_dst[k] == node) {
                int p = atomicAdd(&scnt, 1);
                if (p < CAPN) { esrc[p] = L1_src[k]; eea[p] = L1_ea[k]; }
            }
        }
        __syncthreads();
        int nE = scnt; if (nE > CAPN) nE = CAPN;
        if (tid == 0) { esrc[nE] = v; eea[nE] = eam; }   // self-loop
        __syncthreads();
        nE += 1;

        const float2* x2 = (const float2*)x;
        for (int j = tid; j < nE; j += 256) {            // parallel x gather
            float2 xv = x2[esrc[j]];
            xsA[j] = xv.x; xsB[j] = xv.y;
        }
        __syncthreads();

        float wl0 = Wl1[lane], wl1w = Wl1[64 + lane], bl = bl1[lane];
        float we = We1[lane], at = att1[lane];
        float2 xv = x2[v];
        float xr = xv.x * Wr1[lane] + xv.y * Wr1[64 + lane] + br1[lane];

        for (int k = wq; k < nE; k += 4) {               // scores
            float xl = xsA[k] * wl0 + xsB[k] * wl1w + bl;
            float ev = xl + xr + eea[k] * we;
            ev = ev > 0.f ? ev : 0.2f * ev;
            float p = ev * at;
            for (int o = 32; o >= 1; o >>= 1) p += __shfl_xor(p, o, 64);
            if (lane == 0) scores[k] = p;
        }
        __syncthreads();

        if (wq == 0) {                                   // softmax stats
            float m = -3.4e38f;
            for (int k = lane; k < nE; k += 64) m = fmaxf(m, scores[k]);
            for (int o = 32; o >= 1; o >>= 1) m = fmaxf(m, __shfl_xor(m, o, 64));
            float d = 0.f;
            for (int k = lane; k < nE; k += 64) d += expf(scores[k] - m);
            for (int o = 32; o >= 1; o >>= 1) d += __shfl_xor(d, o, 64);
            if (lane == 0) { m_sh = m; d_sh = d; }
        }
        __syncthreads();
        float m = m_sh, dinv = 1.f / d_sh;

        float acc = 0.f;                                 // weighted sum
        for (int k = wq; k < nE; k += 4) {
            float xl = xsA[k] * wl0 + xsB[k] * wl1w + bl;
            acc += expf(scores[k] - m) * dinv * xl;
        }
        part[wq][lane] = acc;
        __syncthreads();
        if (tid < 64) {
            float h = part[0][lane] + part[1][lane] + part[2][lane] + part[3][lane] + b1[lane];
            hrow[lane] = h > 0.f ? h : 0.f;
        }
        __syncthreads();

        // fused: xl2[node] = Wl2^T hrow + bl2 (k-split across waves)
        float p = 0.f;
        int k0 = 16 * wq;
        for (int k = k0; k < k0 + 16; k++) p += hrow[k] * Wl2[k * 64 + lane];
        part[wq][lane] = p;
        __syncthreads();
        if (tid < 64)
            xl2[node * 64 + lane] = part[0][lane] + part[1][lane] + part[2][lane] + part[3][lane] + bl2[lane];

        if (node == 0) {                                 // target transform -> LDS
            __syncthreads();
            float p2 = 0.f;
            for (int k = k0; k < k0 + 16; k++) p2 += hrow[k] * Wr2[k * 64 + lane];
            part[wq][lane] = p2;
            __syncthreads();
            if (tid < 64)
                xr2s[lane] = part[0][lane] + part[1][lane] + part[2][lane] + part[3][lane] + br2[lane];
        }
        __syncthreads();
    }
    grid_sync(bar, 2);

    // ---------------- phase 5: target layer-2 softmax + head (block 0) ------
    if (bid == 0) {
        int nE2 = c2;
        if (tid < 64) {
            float we = We2[lane], at = att2[lane], xr = xr2s[lane];
            for (int j = 0; j <= nE2; j++) {
                int   idx = (j < nE2) ? l2idx[j] : 0;
                float eav = (j < nE2) ? L2_ea[j] : eam;
                float ev = xl2[idx * 64 + lane] + xr + eav * we;
                ev = ev > 0.f ? ev : 0.2f * ev;
                float p = ev * at;
                for (int o = 32; o >= 1; o >>= 1) p += __shfl_xor(p, o, 64);
                if (lane == 0) scores[j] = p;
            }
            int tot = nE2 + 1;
            float m = -3.4e38f;
            for (int j = lane; j < tot; j += 64) m = fmaxf(m, scores[j]);
            for (int o = 32; o >= 1; o >>= 1) m = fmaxf(m, __shfl_xor(m, o, 64));
            float d = 0.f;
            for (int j = lane; j < tot; j += 64) d += expf(scores[j] - m);
            for (int o = 32; o >= 1; o >>= 1) d += __shfl_xor(d, o, 64);

            float acc = 0.f;
            for (int j = 0; j < tot; j++) {
                int idx = (j < nE2) ? l2idx[j] : 0;
                acc += expf(scores[j] - m) / d * xl2[idx * 64 + lane];
            }
            float h = acc + b2[lane];
            hrow[lane] = h > 0.f ? h : 0.f;
        }
        __syncthreads();
        if (tid < 128) {
            float r = bf[tid];
            for (int c = 0; c < 64; c++) r += hrow[c] * Wf[c * 128 + tid];
            out[tid] = r;
        }
    }
}

extern "C" void kernel_launch(void* const* d_in, const int* in_sizes, int n_in,
                              void* d_out, int out_size, void* d_ws, size_t ws_size,
                              hipStream_t stream) {
    const float* x    = (const float*)d_in[0];
    const int*   ei   = (const int*)  d_in[1];
    const float* ea   = (const float*)d_in[2];
    const int*   tptr = (const int*)  d_in[3];
    const float* Wl1  = (const float*)d_in[4];
    const float* bl1  = (const float*)d_in[5];
    const float* Wr1  = (const float*)d_in[6];
    const float* br1  = (const float*)d_in[7];
    const float* We1  = (const float*)d_in[8];
    const float* att1 = (const float*)d_in[9];
    const float* b1   = (const float*)d_in[10];
    const float* Wl2  = (const float*)d_in[11];
    const float* bl2  = (const float*)d_in[12];
    const float* Wr2  = (const float*)d_in[13];
    const float* br2  = (const float*)d_in[14];
    const float* We2  = (const float*)d_in[15];
    const float* att2 = (const float*)d_in[16];
    const float* b2   = (const float*)d_in[17];
    const float* Wf   = (const float*)d_in[18];
    const float* bf   = (const float*)d_in[19];

    int E = in_sizes[2];

    char* base = (char*)d_ws;
    int*   hdr      = (int*)base;   base += 256;
    int*   bar      = (int*)base;   base += 1792;  // hdr+bar zeroed together
    float* partials = (float*)base; base += NBLK * sizeof(float);
    int*   L2_src   = (int*)base;   base += CAP2 * sizeof(int);
    float* L2_ea    = (float*)base; base += CAP2 * sizeof(float);
    int*   L1_src   = (int*)base;   base += CAP1 * sizeof(int);
    int*   L1_dst   = (int*)base;   base += CAP1 * sizeof(int);
    float* L1_ea    = (float*)base; base += CAP1 * sizeof(float);
    float* xl2      = (float*)base; base += (size_t)CAPS1 * 64 * sizeof(float);

    // Load-bearing: ws is re-poisoned to 0xAA before every timed launch;
    // counters + barrier epochs must start at 0.
    hipMemsetAsync(hdr, 0, 2048, stream);

    hipLaunchKernelGGL(k_mega, dim3(NBLK), dim3(256), 0, stream,
                       x, ei, ea, tptr,
                       Wl1, bl1, Wr1, br1, We1, att1, b1,
                       Wl2, bl2, Wr2, br2, We2, att2, b2,
                       Wf, bf, E,
                       hdr, bar, partials,
                       L2_src, L2_ea,
                       L1_src, L1_dst, L1_ea,
                       xl2, (float*)d_out);
}

// Round 7
// 198.718 us; speedup vs baseline: 2.2935x; 1.0852x over previous
//
#include <hip/hip_runtime.h>
#include <math.h>

#define CAP2   511           // max in-edges of target node (expected ~16)
#define CAPS1  512           // max 1-hop node set size
#define CAP1   65536         // max edges into S1 nodes (expected ~300)
#define CAPN   512           // per-node in-edge cap in layer-1 phase
#define NBLK   256           // persistent grid: 1 block/CU — co-residency guaranteed
#define NGRP   8
#define GRPSZ  (NBLK / NGRP)

// ws layout: hdr (256 B: [0]=cnt2, [8]=cnt1) | bar (1792 B) | data arrays.
// hdr+bar zeroed by hipMemsetAsync every call (ws is re-poisoned to 0xAA).
//
// COHERENCE DESIGN (R7): all cross-phase data moves through agent-scope
// RELAXED atomics (sc1 -> LLC, bypassing non-coherent XCD L2s). The barrier
// therefore needs NO fences: __syncthreads() lowers to s_waitcnt vmcnt(0)
// + s_barrier, so every sc1 store of the block is at the LLC before thread 0
// arrives. R6's ACQ_REL/fence barrier emitted buffer_wbl2+buffer_inv per
// arrival -> 73 MB of poison write-backs + L2 nukes -> 118 us of stall.

__device__ __forceinline__ int aload_i(const int* p) {
    return __hip_atomic_load((int*)p, __ATOMIC_RELAXED, __HIP_MEMORY_SCOPE_AGENT);
}
__device__ __forceinline__ void astore_i(int* p, int v) {
    __hip_atomic_store(p, v, __ATOMIC_RELAXED, __HIP_MEMORY_SCOPE_AGENT);
}
__device__ __forceinline__ float aload_f(const float* p) {
    return __hip_atomic_load((float*)p, __ATOMIC_RELAXED, __HIP_MEMORY_SCOPE_AGENT);
}
__device__ __forceinline__ void astore_f(float* p, float v) {
    __hip_atomic_store(p, v, __ATOMIC_RELAXED, __HIP_MEMORY_SCOPE_AGENT);
}

// Monotonic hierarchical barrier, all RELAXED (no cache-maintenance ops).
__device__ __forceinline__ void grid_sync(int* bar, int epoch) {
    __syncthreads();   // drains vmcnt: block's sc1 stores are at LLC
    if (threadIdx.x == 0) {
        int g = blockIdx.x & (NGRP - 1);
        int prev = __hip_atomic_fetch_add(&bar[32 * g], 1,
                     __ATOMIC_RELAXED, __HIP_MEMORY_SCOPE_AGENT);
        if (prev == (epoch + 1) * GRPSZ - 1) {            // last of group
            int p2 = __hip_atomic_fetch_add(&bar[256], 1,
                       __ATOMIC_RELAXED, __HIP_MEMORY_SCOPE_AGENT);
            if (p2 == (epoch + 1) * NGRP - 1)             // last group
                __hip_atomic_store(&bar[288], epoch + 1,
                    __ATOMIC_RELAXED, __HIP_MEMORY_SCOPE_AGENT);
        }
        while (__hip_atomic_load(&bar[288], __ATOMIC_RELAXED,
                                 __HIP_MEMORY_SCOPE_AGENT) < epoch + 1)
            __builtin_amdgcn_s_sleep(2);
    }
    __syncthreads();
}

__global__ __launch_bounds__(256, 4)
void k_mega(const float* __restrict__ x, const int* __restrict__ ei,
            const float* __restrict__ ea, const int* __restrict__ tptr,
            const float* __restrict__ Wl1, const float* __restrict__ bl1,
            const float* __restrict__ Wr1, const float* __restrict__ br1,
            const float* __restrict__ We1, const float* __restrict__ att1,
            const float* __restrict__ b1,
            const float* __restrict__ Wl2, const float* __restrict__ bl2,
            const float* __restrict__ Wr2, const float* __restrict__ br2,
            const float* __restrict__ We2, const float* __restrict__ att2,
            const float* __restrict__ b2,
            const float* __restrict__ Wf, const float* __restrict__ bf,
            int E,
            int* hdr, int* bar, float* partials,
            int* L2_src, float* L2_ea,
            int* L1_src, int* L1_dst, float* L1_ea,
            float* xl2, float* out) {
    int tid = threadIdx.x, lane = tid & 63, wq = tid >> 6;
    int bid = blockIdx.x;
    int gid = bid * 256 + tid;
    const int gstride = NBLK * 256;

    __shared__ float wsum[4];
    __shared__ int   s1[CAPS1];
    __shared__ int   l2idx[CAP2];
    __shared__ int   esrc[CAPN + 1];
    __shared__ float eea[CAPN + 1];
    __shared__ float xsA[CAPN + 1], xsB[CAPN + 1];
    __shared__ float scores[CAPN + 1];
    __shared__ float part[4][64];
    __shared__ float hrow[64];
    __shared__ float xr2s[64];
    __shared__ float m_sh, d_sh, eam_sh;
    __shared__ int   n_sh, scnt;

    // ---------------- phase 1: scanA (target in-edges + ea partial sums) ----
    {
        int t = tptr[0];
        float local = 0.f;
        const int4*   dst4 = (const int4*)(ei + E);
        const float4* ea4  = (const float4*)ea;
        int E4 = E >> 2;
        for (int e4 = gid; e4 < E4; e4 += gstride) {
            int4 d = dst4[e4];
            float4 a = ea4[e4];
            local += a.x + a.y + a.z + a.w;
            int eb = e4 * 4;
            if (d.x == t) { int p = atomicAdd(&hdr[0], 1); if (p < CAP2) { astore_i(&L2_src[p], ei[eb]);     astore_f(&L2_ea[p], a.x); } }
            if (d.y == t) { int p = atomicAdd(&hdr[0], 1); if (p < CAP2) { astore_i(&L2_src[p], ei[eb + 1]); astore_f(&L2_ea[p], a.y); } }
            if (d.z == t) { int p = atomicAdd(&hdr[0], 1); if (p < CAP2) { astore_i(&L2_src[p], ei[eb + 2]); astore_f(&L2_ea[p], a.z); } }
            if (d.w == t) { int p = atomicAdd(&hdr[0], 1); if (p < CAP2) { astore_i(&L2_src[p], ei[eb + 3]); astore_f(&L2_ea[p], a.w); } }
        }
        if (gid == 0) {                  // tail (E % 4)
            for (int e = E4 * 4; e < E; e++) {
                float a = ea[e];
                local += a;
                if (ei[E + e] == t) { int p = atomicAdd(&hdr[0], 1); if (p < CAP2) { astore_i(&L2_src[p], ei[e]); astore_f(&L2_ea[p], a); } }
            }
        }
        for (int o = 32; o >= 1; o >>= 1) local += __shfl_xor(local, o, 64);
        if (lane == 0) wsum[wq] = local;
        __syncthreads();
        if (tid == 0) astore_f(&partials[bid], wsum[0] + wsum[1] + wsum[2] + wsum[3]);
    }
    grid_sync(bar, 0);

    // ------- phase 2+3 (merged, all blocks redundantly): ea_sum reduce, -----
    // ------- S1 dedupe into LDS, then scanC over all edges ------------------
    int c2 = aload_i(&hdr[0]); if (c2 > CAP2) c2 = CAP2;
    {
        float local = aload_f(&partials[tid]);            // NBLK == 256
        for (int o = 32; o >= 1; o >>= 1) local += __shfl_xor(local, o, 64);
        if (lane == 0) wsum[wq] = local;
        // preload L2_src into LDS (parallel) for the serial dedupe
        for (int k = tid; k < c2; k += 256) esrc[k] = aload_i(&L2_src[k]);
        __syncthreads();
        if (tid == 0) {
            eam_sh = (wsum[0] + wsum[1] + wsum[2] + wsum[3]) / (float)E;
            int t = tptr[0];
            s1[0] = t;
            int n = 1;
            for (int k = 0; k < c2; k++) {
                int v = esrc[k];
                int idx = -1;
                for (int j = 0; j < n; j++) if (s1[j] == v) { idx = j; break; }
                if (idx < 0) { idx = n; s1[n] = v; n++; }
                l2idx[k] = idx;
            }
            n_sh = n;
        }
        __syncthreads();
        int n_s1 = n_sh;
        const int4* dst4 = (const int4*)(ei + E);
        int E4 = E >> 2;
        for (int e4 = gid; e4 < E4; e4 += gstride) {
            int4 d = dst4[e4];
            int eb = e4 * 4;
            int dd[4] = {d.x, d.y, d.z, d.w};
            #pragma unroll
            for (int q = 0; q < 4; q++) {
                int idx = -1;
                for (int j = 0; j < n_s1; j++) if (s1[j] == dd[q]) { idx = j; break; }
                if (idx >= 0) {
                    int p = atomicAdd(&hdr[8], 1);
                    if (p < CAP1) { astore_i(&L1_src[p], ei[eb + q]); astore_i(&L1_dst[p], idx); astore_f(&L1_ea[p], ea[eb + q]); }
                }
            }
        }
        if (gid == 0) {
            for (int e = E4 * 4; e < E; e++) {
                int dv = ei[E + e];
                int idx = -1;
                for (int j = 0; j < n_s1; j++) if (s1[j] == dv) { idx = j; break; }
                if (idx >= 0) {
                    int p = atomicAdd(&hdr[8], 1);
                    if (p < CAP1) { astore_i(&L1_src[p], ei[e]); astore_i(&L1_dst[p], idx); astore_f(&L1_ea[p], ea[e]); }
                }
            }
        }
    }
    grid_sync(bar, 1);

    int n_s1 = n_sh;
    float eam = eam_sh;

    // ---------------- phase 4: layer 1 + fused layer-2 transforms -----------
    for (int node = bid; node < n_s1; node += NBLK) {
        int v = s1[node];
        if (tid == 0) scnt = 0;
        __syncthreads();

        int c1 = aload_i(&hdr[8]); if (c1 > CAP1) c1 = CAP1;
        for (int k = tid; k < c1; k += 256) {
            if (aload_i(&L1_dst[k]) == node) {
                int p = atomicAdd(&scnt, 1);
                if (p < CAPN) { esrc[p] = aload_i(&L1_src[k]); eea[p] = aload_f(&L1_ea[k]); }
            }
        }
        __syncthreads();
        int nE = scnt; if (nE > CAPN) nE = CAPN;
        if (tid == 0) { esrc[nE] = v; eea[nE] = eam; }   // self-loop
        __syncthreads();
        nE += 1;

        const float2* x2 = (const float2*)x;
        for (int j = tid; j < nE; j += 256) {            // parallel x gather
            float2 xv = x2[esrc[j]];
            xsA[j] = xv.x; xsB[j] = xv.y;
        }
        __syncthreads();

        float wl0 = Wl1[lane], wl1w = Wl1[64 + lane], bl = bl1[lane];
        float we = We1[lane], at = att1[lane];
        float2 xv = x2[v];
        float xr = xv.x * Wr1[lane] + xv.y * Wr1[64 + lane] + br1[lane];

        for (int k = wq; k < nE; k += 4) {               // scores
            float xl = xsA[k] * wl0 + xsB[k] * wl1w + bl;
            float ev = xl + xr + eea[k] * we;
            ev = ev > 0.f ? ev : 0.2f * ev;
            float p = ev * at;
            for (int o = 32; o >= 1; o >>= 1) p += __shfl_xor(p, o, 64);
            if (lane == 0) scores[k] = p;
        }
        __syncthreads();

        if (wq == 0) {                                   // softmax stats
            float m = -3.4e38f;
            for (int k = lane; k < nE; k += 64) m = fmaxf(m, scores[k]);
            for (int o = 32; o >= 1; o >>= 1) m = fmaxf(m, __shfl_xor(m, o, 64));
            float d = 0.f;
            for (int k = lane; k < nE; k += 64) d += expf(scores[k] - m);
            for (int o = 32; o >= 1; o >>= 1) d += __shfl_xor(d, o, 64);
            if (lane == 0) { m_sh = m; d_sh = d; }
        }
        __syncthreads();
        float m = m_sh, dinv = 1.f / d_sh;

        float acc = 0.f;                                 // weighted sum
        for (int k = wq; k < nE; k += 4) {
            float xl = xsA[k] * wl0 + xsB[k] * wl1w + bl;
            acc += expf(scores[k] - m) * dinv * xl;
        }
        part[wq][lane] = acc;
        __syncthreads();
        if (tid < 64) {
            float h = part[0][lane] + part[1][lane] + part[2][lane] + part[3][lane] + b1[lane];
            hrow[lane] = h > 0.f ? h : 0.f;
        }
        __syncthreads();

        // fused: xl2[node] = Wl2^T hrow + bl2 (k-split across waves)
        float p = 0.f;
        int k0 = 16 * wq;
        for (int k = k0; k < k0 + 16; k++) p += hrow[k] * Wl2[k * 64 + lane];
        part[wq][lane] = p;
        __syncthreads();
        if (tid < 64)
            astore_f(&xl2[node * 64 + lane],
                     part[0][lane] + part[1][lane] + part[2][lane] + part[3][lane] + bl2[lane]);

        if (node == 0) {                                 // target transform -> LDS
            __syncthreads();
            float p2 = 0.f;
            for (int k = k0; k < k0 + 16; k++) p2 += hrow[k] * Wr2[k * 64 + lane];
            part[wq][lane] = p2;
            __syncthreads();
            if (tid < 64)
                xr2s[lane] = part[0][lane] + part[1][lane] + part[2][lane] + part[3][lane] + br2[lane];
        }
        __syncthreads();
    }
    grid_sync(bar, 2);

    // ---------------- phase 5: target layer-2 softmax + head (block 0) ------
    if (bid == 0) {
        int nE2 = c2;
        if (tid < 64) {
            float we = We2[lane], at = att2[lane], xr = xr2s[lane];
            for (int j = 0; j <= nE2; j++) {
                int   idx = (j < nE2) ? l2idx[j] : 0;
                float eav = (j < nE2) ? aload_f(&L2_ea[j]) : eam;
                float ev = aload_f(&xl2[idx * 64 + lane]) + xr + eav * we;
                ev = ev > 0.f ? ev : 0.2f * ev;
                float p = ev * at;
                for (int o = 32; o >= 1; o >>= 1) p += __shfl_xor(p, o, 64);
                if (lane == 0) scores[j] = p;
            }
            int tot = nE2 + 1;
            float m = -3.4e38f;
            for (int j = lane; j < tot; j += 64) m = fmaxf(m, scores[j]);
            for (int o = 32; o >= 1; o >>= 1) m = fmaxf(m, __shfl_xor(m, o, 64));
            float d = 0.f;
            for (int j = lane; j < tot; j += 64) d += expf(scores[j] - m);
            for (int o = 32; o >= 1; o >>= 1) d += __shfl_xor(d, o, 64);

            float acc = 0.f;
            for (int j = 0; j < tot; j++) {
                int idx = (j < nE2) ? l2idx[j] : 0;
                acc += expf(scores[j] - m) / d * aload_f(&xl2[idx * 64 + lane]);
            }
            float h = acc + b2[lane];
            hrow[lane] = h > 0.f ? h : 0.f;
        }
        __syncthreads();
        if (tid < 128) {
            float r = bf[tid];
            for (int c = 0; c < 64; c++) r += hrow[c] * Wf[c * 128 + tid];
            out[tid] = r;
        }
    }
}

extern "C" void kernel_launch(void* const* d_in, const int* in_sizes, int n_in,
                              void* d_out, int out_size, void* d_ws, size_t ws_size,
                              hipStream_t stream) {
    const float* x    = (const float*)d_in[0];
    const int*   ei   = (const int*)  d_in[1];
    const float* ea   = (const float*)d_in[2];
    const int*   tptr = (const int*)  d_in[3];
    const float* Wl1  = (const float*)d_in[4];
    const float* bl1  = (const float*)d_in[5];
    const float* Wr1  = (const float*)d_in[6];
    const float* br1  = (const float*)d_in[7];
    const float* We1  = (const float*)d_in[8];
    const float* att1 = (const float*)d_in[9];
    const float* b1   = (const float*)d_in[10];
    const float* Wl2  = (const float*)d_in[11];
    const float* bl2  = (const float*)d_in[12];
    const float* Wr2  = (const float*)d_in[13];
    const float* br2  = (const float*)d_in[14];
    const float* We2  = (const float*)d_in[15];
    const float* att2 = (const float*)d_in[16];
    const float* b2   = (const float*)d_in[17];
    const float* Wf   = (const float*)d_in[18];
    const float* bf   = (const float*)d_in[19];

    int E = in_sizes[2];

    char* base = (char*)d_ws;
    int*   hdr      = (int*)base;   base += 256;
    int*   bar      = (int*)base;   base += 1792;  // hdr+bar zeroed together
    float* partials = (float*)base; base += NBLK * sizeof(float);
    int*   L2_src   = (int*)base;   base += CAP2 * sizeof(int);
    float* L2_ea    = (float*)base; base += CAP2 * sizeof(float);
    int*   L1_src   = (int*)base;   base += CAP1 * sizeof(int);
    int*   L1_dst   = (int*)base;   base += CAP1 * sizeof(int);
    float* L1_ea    = (float*)base; base += CAP1 * sizeof(float);
    float* xl2      = (float*)base; base += (size_t)CAPS1 * 64 * sizeof(float);

    // Load-bearing: ws is re-poisoned to 0xAA before every timed launch;
    // counters + barrier epochs must start at 0.
    hipMemsetAsync(hdr, 0, 2048, stream);

    hipLaunchKernelGGL(k_mega, dim3(NBLK), dim3(256), 0, stream,
                       x, ei, ea, tptr,
                       Wl1, bl1, Wr1, br1, We1, att1, b1,
                       Wl2, bl2, Wr2, br2, We2, att2, b2,
                       Wf, bf, E,
                       hdr, bar, partials,
                       L2_src, L2_ea,
                       L1_src, L1_dst, L1_ea,
                       xl2, (float*)d_out);
}

// Round 8
// 132.577 us; speedup vs baseline: 3.4377x; 1.4989x over previous
//
#include <hip/hip_runtime.h>
#include <math.h>

#define CAP2   511           // max in-edges of target node (expected ~16)
#define CAPS1  512           // max 1-hop node set size
#define CAP1   65536         // max edges into S1 nodes (expected ~300)
#define CAPN   512           // per-node in-edge cap in layer-1 phase
#define NBLK   512           // persistent grid: 2 blocks/CU needed, 4/CU capacity
#define NGRP   8
#define GRPSZ  (NBLK / NGRP)
#define BMW    4096          // bitmap words (2^17 bits); exact for N < 131072

// ws layout: hdr (256 B: [0]=cnt2, [8]=cnt1) | bar (1792 B) | data arrays.
// hdr+bar zeroed by hipMemsetAsync every call (ws is re-poisoned to 0xAA).
// All cross-phase data via agent-scope RELAXED atomics (sc1 -> LLC, bypassing
// non-coherent XCD L2s); barrier is fence-free (R7, verified absmax 0.0).
// R8: kill serialized latency chains (bitmap membership, ballot dedupe,
// parallel phase 5, 2 blocks/CU) — R7 was latency-bound at VALUBusy 3.8%.

__device__ __forceinline__ int aload_i(const int* p) {
    return __hip_atomic_load((int*)p, __ATOMIC_RELAXED, __HIP_MEMORY_SCOPE_AGENT);
}
__device__ __forceinline__ void astore_i(int* p, int v) {
    __hip_atomic_store(p, v, __ATOMIC_RELAXED, __HIP_MEMORY_SCOPE_AGENT);
}
__device__ __forceinline__ float aload_f(const float* p) {
    return __hip_atomic_load((float*)p, __ATOMIC_RELAXED, __HIP_MEMORY_SCOPE_AGENT);
}
__device__ __forceinline__ void astore_f(float* p, float v) {
    __hip_atomic_store(p, v, __ATOMIC_RELAXED, __HIP_MEMORY_SCOPE_AGENT);
}

// Monotonic hierarchical barrier, all RELAXED (no cache-maintenance ops).
__device__ __forceinline__ void grid_sync(int* bar, int epoch) {
    __syncthreads();   // drains vmcnt: block's sc1 stores are at LLC
    if (threadIdx.x == 0) {
        int g = blockIdx.x & (NGRP - 1);
        int prev = __hip_atomic_fetch_add(&bar[32 * g], 1,
                     __ATOMIC_RELAXED, __HIP_MEMORY_SCOPE_AGENT);
        if (prev == (epoch + 1) * GRPSZ - 1) {            // last of group
            int p2 = __hip_atomic_fetch_add(&bar[256], 1,
                       __ATOMIC_RELAXED, __HIP_MEMORY_SCOPE_AGENT);
            if (p2 == (epoch + 1) * NGRP - 1)             // last group
                __hip_atomic_store(&bar[288], epoch + 1,
                    __ATOMIC_RELAXED, __HIP_MEMORY_SCOPE_AGENT);
        }
        while (__hip_atomic_load(&bar[288], __ATOMIC_RELAXED,
                                 __HIP_MEMORY_SCOPE_AGENT) < epoch + 1)
            __builtin_amdgcn_s_sleep(2);
    }
    __syncthreads();
}

__global__ __launch_bounds__(256, 4)
void k_mega(const float* __restrict__ x, const int* __restrict__ ei,
            const float* __restrict__ ea, const int* __restrict__ tptr,
            const float* __restrict__ Wl1, const float* __restrict__ bl1,
            const float* __restrict__ Wr1, const float* __restrict__ br1,
            const float* __restrict__ We1, const float* __restrict__ att1,
            const float* __restrict__ b1,
            const float* __restrict__ Wl2, const float* __restrict__ bl2,
            const float* __restrict__ Wr2, const float* __restrict__ br2,
            const float* __restrict__ We2, const float* __restrict__ att2,
            const float* __restrict__ b2,
            const float* __restrict__ Wf, const float* __restrict__ bf,
            int E,
            int* hdr, int* bar, float* partials,
            int* L2_src, float* L2_ea,
            int* L1_src, int* L1_dst, float* L1_ea,
            float* xl2, float* out) {
    int tid = threadIdx.x, lane = tid & 63, wq = tid >> 6;
    int bid = blockIdx.x;
    int gid = bid * 256 + tid;
    const int gstride = NBLK * 256;

    __shared__ float wsum[4];
    __shared__ int   s1[CAPS1];
    __shared__ int   l2idx[CAP2];
    __shared__ int   esrc[CAPN + 1];
    __shared__ float eea[CAPN + 1];
    __shared__ float xsA[CAPN + 1], xsB[CAPN + 1];
    __shared__ float scores[CAPN + 1];
    __shared__ float part[4][64];
    __shared__ float hrow[64];
    __shared__ float xr2s[64];
    __shared__ int   bitmap[BMW];      // phase 3; reused as xl2sh in phase 5
    __shared__ float m_sh, d_sh, eam_sh;
    __shared__ int   n_sh, scnt;

    // ---------------- phase 1: scanA (target in-edges + ea partial sums) ----
    {
        int t = tptr[0];
        float local = 0.f;
        const int4*   dst4 = (const int4*)(ei + E);
        const float4* ea4  = (const float4*)ea;
        int E4 = E >> 2;
        for (int e4 = gid; e4 < E4; e4 += gstride) {
            int4 d = dst4[e4];
            float4 a = ea4[e4];
            local += a.x + a.y + a.z + a.w;
            int eb = e4 * 4;
            if (d.x == t) { int p = atomicAdd(&hdr[0], 1); if (p < CAP2) { astore_i(&L2_src[p], ei[eb]);     astore_f(&L2_ea[p], a.x); } }
            if (d.y == t) { int p = atomicAdd(&hdr[0], 1); if (p < CAP2) { astore_i(&L2_src[p], ei[eb + 1]); astore_f(&L2_ea[p], a.y); } }
            if (d.z == t) { int p = atomicAdd(&hdr[0], 1); if (p < CAP2) { astore_i(&L2_src[p], ei[eb + 2]); astore_f(&L2_ea[p], a.z); } }
            if (d.w == t) { int p = atomicAdd(&hdr[0], 1); if (p < CAP2) { astore_i(&L2_src[p], ei[eb + 3]); astore_f(&L2_ea[p], a.w); } }
        }
        if (gid == 0) {                  // tail (E % 4)
            for (int e = (E >> 2) * 4; e < E; e++) {
                float a = ea[e];
                local += a;
                if (ei[E + e] == t) { int p = atomicAdd(&hdr[0], 1); if (p < CAP2) { astore_i(&L2_src[p], ei[e]); astore_f(&L2_ea[p], a); } }
            }
        }
        for (int o = 32; o >= 1; o >>= 1) local += __shfl_xor(local, o, 64);
        if (lane == 0) wsum[wq] = local;
        __syncthreads();
        if (tid == 0) astore_f(&partials[bid], wsum[0] + wsum[1] + wsum[2] + wsum[3]);
    }
    grid_sync(bar, 0);

    // ------- phase 2+3 (merged, all blocks redundantly): ea_sum reduce, -----
    // ------- ballot dedupe of S1, bitmap build, then scanC over all edges ---
    int c2 = aload_i(&hdr[0]); if (c2 > CAP2) c2 = CAP2;
    {
        float local = aload_f(&partials[tid]) + aload_f(&partials[tid + 256]);
        for (int o = 32; o >= 1; o >>= 1) local += __shfl_xor(local, o, 64);
        if (lane == 0) wsum[wq] = local;
        __syncthreads();
        if (tid == 0) eam_sh = (wsum[0] + wsum[1] + wsum[2] + wsum[3]) / (float)E;

        // --- dedupe: wave 0, ballot/shuffle fast path for c2 <= 64 ---------
        if (wq == 0) {
            int t = tptr[0];
            if (c2 <= 64) {
                int v = (lane < c2) ? aload_i(&L2_src[lane]) : -1;
                int first = lane;
                #pragma unroll
                for (int j = 0; j < 64; j++) {
                    int vj = __shfl(v, j);
                    if (j < first && vj == v) first = j;   // earliest equal lane
                }
                bool isfirst = (lane < c2) && (first == lane) && (v != t);
                unsigned long long bf = __ballot(isfirst);
                int myidx = (v == t) ? 0
                            : (1 + (int)__popcll(bf & ((1ull << lane) - 1)));
                int idx = __shfl(myidx, first);
                if (lane < c2) l2idx[lane] = idx;
                if (isfirst) s1[myidx] = v;
                if (lane == 0) { s1[0] = t; n_sh = 1 + (int)__popcll(bf); }
            } else if (lane == 0) {                        // serial fallback
                s1[0] = t;
                int n = 1;
                for (int k = 0; k < c2; k++) {
                    int v = aload_i(&L2_src[k]);
                    int idx = -1;
                    for (int j = 0; j < n; j++) if (s1[j] == v) { idx = j; break; }
                    if (idx < 0) { idx = n; s1[n] = v; n++; }
                    l2idx[k] = idx;
                }
                n_sh = n;
            }
        }
        // --- bitmap build --------------------------------------------------
        for (int w = tid; w < BMW; w += 256) bitmap[w] = 0;
        __syncthreads();
        int n_s1 = n_sh;
        for (int j = tid; j < n_s1; j += 256) {
            int u = s1[j];
            atomicOr(&bitmap[(u >> 5) & (BMW - 1)], 1 << (u & 31));
        }
        __syncthreads();

        // --- scanC: bitmap test (1 independent ds_read/edge), verify on hit -
        const int4* dst4 = (const int4*)(ei + E);
        int E4 = E >> 2;
        for (int e4 = gid; e4 < E4; e4 += gstride) {
            int4 d = dst4[e4];
            int eb = e4 * 4;
            int dd[4] = {d.x, d.y, d.z, d.w};
            #pragma unroll
            for (int q = 0; q < 4; q++) {
                int dv = dd[q];
                if (bitmap[(dv >> 5) & (BMW - 1)] & (1 << (dv & 31))) {
                    int idx = -1;
                    for (int j = 0; j < n_s1; j++) if (s1[j] == dv) { idx = j; break; }
                    if (idx >= 0) {
                        int p = atomicAdd(&hdr[8], 1);
                        if (p < CAP1) { astore_i(&L1_src[p], ei[eb + q]); astore_i(&L1_dst[p], idx); astore_f(&L1_ea[p], ea[eb + q]); }
                    }
                }
            }
        }
        if (gid == 0) {
            for (int e = E4 * 4; e < E; e++) {
                int dv = ei[E + e];
                int idx = -1;
                for (int j = 0; j < n_s1; j++) if (s1[j] == dv) { idx = j; break; }
                if (idx >= 0) {
                    int p = atomicAdd(&hdr[8], 1);
                    if (p < CAP1) { astore_i(&L1_src[p], ei[e]); astore_i(&L1_dst[p], idx); astore_f(&L1_ea[p], ea[e]); }
                }
            }
        }
    }
    grid_sync(bar, 1);

    int n_s1 = n_sh;
    float eam = eam_sh;

    // ---------------- phase 4: layer 1 + fused layer-2 transforms -----------
    for (int node = bid; node < n_s1; node += NBLK) {
        int v = s1[node];
        if (tid == 0) scnt = 0;
        __syncthreads();

        int c1 = aload_i(&hdr[8]); if (c1 > CAP1) c1 = CAP1;
        for (int k = tid; k < c1; k += 256) {
            if (aload_i(&L1_dst[k]) == node) {
                int p = atomicAdd(&scnt, 1);
                if (p < CAPN) { esrc[p] = aload_i(&L1_src[k]); eea[p] = aload_f(&L1_ea[k]); }
            }
        }
        __syncthreads();
        int nE = scnt; if (nE > CAPN) nE = CAPN;
        if (tid == 0) { esrc[nE] = v; eea[nE] = eam; }   // self-loop
        __syncthreads();
        nE += 1;

        const float2* x2 = (const float2*)x;
        for (int j = tid; j < nE; j += 256) {            // parallel x gather
            float2 xv = x2[esrc[j]];
            xsA[j] = xv.x; xsB[j] = xv.y;
        }
        __syncthreads();

        float wl0 = Wl1[lane], wl1w = Wl1[64 + lane], bl = bl1[lane];
        float we = We1[lane], at = att1[lane];
        float2 xv = x2[v];
        float xr = xv.x * Wr1[lane] + xv.y * Wr1[64 + lane] + br1[lane];

        for (int k = wq; k < nE; k += 4) {               // scores
            float xl = xsA[k] * wl0 + xsB[k] * wl1w + bl;
            float ev = xl + xr + eea[k] * we;
            ev = ev > 0.f ? ev : 0.2f * ev;
            float p = ev * at;
            for (int o = 32; o >= 1; o >>= 1) p += __shfl_xor(p, o, 64);
            if (lane == 0) scores[k] = p;
        }
        __syncthreads();

        if (wq == 0) {                                   // softmax stats
            float m = -3.4e38f;
            for (int k = lane; k < nE; k += 64) m = fmaxf(m, scores[k]);
            for (int o = 32; o >= 1; o >>= 1) m = fmaxf(m, __shfl_xor(m, o, 64));
            float d = 0.f;
            for (int k = lane; k < nE; k += 64) d += expf(scores[k] - m);
            for (int o = 32; o >= 1; o >>= 1) d += __shfl_xor(d, o, 64);
            if (lane == 0) { m_sh = m; d_sh = d; }
        }
        __syncthreads();
        float m = m_sh, dinv = 1.f / d_sh;

        float acc = 0.f;                                 // weighted sum
        for (int k = wq; k < nE; k += 4) {
            float xl = xsA[k] * wl0 + xsB[k] * wl1w + bl;
            acc += expf(scores[k] - m) * dinv * xl;
        }
        part[wq][lane] = acc;
        __syncthreads();
        if (tid < 64) {
            float h = part[0][lane] + part[1][lane] + part[2][lane] + part[3][lane] + b1[lane];
            hrow[lane] = h > 0.f ? h : 0.f;
        }
        __syncthreads();

        // fused: xl2[node] = Wl2^T hrow + bl2 (k-split across waves)
        float p = 0.f;
        int k0 = 16 * wq;
        for (int k = k0; k < k0 + 16; k++) p += hrow[k] * Wl2[k * 64 + lane];
        part[wq][lane] = p;
        __syncthreads();
        if (tid < 64)
            astore_f(&xl2[node * 64 + lane],
                     part[0][lane] + part[1][lane] + part[2][lane] + part[3][lane] + bl2[lane]);

        if (node == 0) {                                 // target transform -> LDS
            __syncthreads();
            float p2 = 0.f;
            for (int k = k0; k < k0 + 16; k++) p2 += hrow[k] * Wr2[k * 64 + lane];
            part[wq][lane] = p2;
            __syncthreads();
            if (tid < 64)
                xr2s[lane] = part[0][lane] + part[1][lane] + part[2][lane] + part[3][lane] + br2[lane];
        }
        __syncthreads();
    }
    grid_sync(bar, 2);

    // -------- phase 5 (block 0, all 4 waves): layer-2 softmax + head --------
    if (bid == 0) {
        int nE2 = c2;
        float* xl2sh = (float*)bitmap;                   // reuse 16 KB
        int rows = n_s1 < 64 ? n_s1 : 64;
        for (int i = tid; i < rows * 64; i += 256) xl2sh[i] = aload_f(&xl2[i]);
        for (int j = tid; j < nE2; j += 256) eea[j] = aload_f(&L2_ea[j]);
        __syncthreads();

        float we = We2[lane], at = att2[lane], xr = xr2s[lane];
        for (int j = wq; j <= nE2; j += 4) {             // scores over waves
            int   idx = (j < nE2) ? l2idx[j] : 0;
            float eav = (j < nE2) ? eea[j]   : eam;
            float xlv = (idx < 64) ? xl2sh[idx * 64 + lane]
                                   : aload_f(&xl2[idx * 64 + lane]);
            float ev = xlv + xr + eav * we;
            ev = ev > 0.f ? ev : 0.2f * ev;
            float p = ev * at;
            for (int o = 32; o >= 1; o >>= 1) p += __shfl_xor(p, o, 64);
            if (lane == 0) scores[j] = p;
        }
        __syncthreads();

        if (wq == 0) {                                   // softmax stats
            int tot = nE2 + 1;
            float m = -3.4e38f;
            for (int j = lane; j < tot; j += 64) m = fmaxf(m, scores[j]);
            for (int o = 32; o >= 1; o >>= 1) m = fmaxf(m, __shfl_xor(m, o, 64));
            float d = 0.f;
            for (int j = lane; j < tot; j += 64) d += expf(scores[j] - m);
            for (int o = 32; o >= 1; o >>= 1) d += __shfl_xor(d, o, 64);
            if (lane == 0) { m_sh = m; d_sh = d; }
        }
        __syncthreads();
        float m = m_sh, dinv = 1.f / d_sh;

        float acc = 0.f;                                 // weighted sum over waves
        for (int j = wq; j <= nE2; j += 4) {
            int idx = (j < nE2) ? l2idx[j] : 0;
            float xlv = (idx < 64) ? xl2sh[idx * 64 + lane]
                                   : aload_f(&xl2[idx * 64 + lane]);
            acc += expf(scores[j] - m) * dinv * xlv;
        }
        part[wq][lane] = acc;
        __syncthreads();
        if (tid < 64) {
            float h = part[0][lane] + part[1][lane] + part[2][lane] + part[3][lane] + b2[lane];
            hrow[lane] = h > 0.f ? h : 0.f;
        }
        __syncthreads();
        if (tid < 128) {                                 // head: [64]@[64,128]+bf
            float r = bf[tid];
            for (int c = 0; c < 64; c++) r += hrow[c] * Wf[c * 128 + tid];
            out[tid] = r;
        }
    }
}

extern "C" void kernel_launch(void* const* d_in, const int* in_sizes, int n_in,
                              void* d_out, int out_size, void* d_ws, size_t ws_size,
                              hipStream_t stream) {
    const float* x    = (const float*)d_in[0];
    const int*   ei   = (const int*)  d_in[1];
    const float* ea   = (const float*)d_in[2];
    const int*   tptr = (const int*)  d_in[3];
    const float* Wl1  = (const float*)d_in[4];
    const float* bl1  = (const float*)d_in[5];
    const float* Wr1  = (const float*)d_in[6];
    const float* br1  = (const float*)d_in[7];
    const float* We1  = (const float*)d_in[8];
    const float* att1 = (const float*)d_in[9];
    const float* b1   = (const float*)d_in[10];
    const float* Wl2  = (const float*)d_in[11];
    const float* bl2  = (const float*)d_in[12];
    const float* Wr2  = (const float*)d_in[13];
    const float* br2  = (const float*)d_in[14];
    const float* We2  = (const float*)d_in[15];
    const float* att2 = (const float*)d_in[16];
    const float* b2   = (const float*)d_in[17];
    const float* Wf   = (const float*)d_in[18];
    const float* bf   = (const float*)d_in[19];

    int E = in_sizes[2];

    char* base = (char*)d_ws;
    int*   hdr      = (int*)base;   base += 256;
    int*   bar      = (int*)base;   base += 1792;  // hdr+bar zeroed together
    float* partials = (float*)base; base += NBLK * sizeof(float);
    int*   L2_src   = (int*)base;   base += CAP2 * sizeof(int);
    float* L2_ea    = (float*)base; base += CAP2 * sizeof(float);
    int*   L1_src   = (int*)base;   base += CAP1 * sizeof(int);
    int*   L1_dst   = (int*)base;   base += CAP1 * sizeof(int);
    float* L1_ea    = (float*)base; base += CAP1 * sizeof(float);
    float* xl2      = (float*)base; base += (size_t)CAPS1 * 64 * sizeof(float);

    // Load-bearing: ws is re-poisoned to 0xAA before every timed launch;
    // counters + barrier epochs must start at 0.
    hipMemsetAsync(hdr, 0, 2048, stream);

    hipLaunchKernelGGL(k_mega, dim3(NBLK), dim3(256), 0, stream,
                       x, ei, ea, tptr,
                       Wl1, bl1, Wr1, br1, We1, att1, b1,
                       Wl2, bl2, Wr2, br2, We2, att2, b2,
                       Wf, bf, E,
                       hdr, bar, partials,
                       L2_src, L2_ea,
                       L1_src, L1_dst, L1_ea,
                       xl2, (float*)d_out);
}

// Round 9
// 130.820 us; speedup vs baseline: 3.4838x; 1.0134x over previous
//
#include <hip/hip_runtime.h>
#include <math.h>

#define CAP2   511           // max in-edges of target node (expected ~16)
#define CAPS1  512           // max 1-hop node set size (== NBLK guard)
#define CAPN   512           // per-node bucket capacity
#define NBLK   512           // persistent grid: 2 blocks/CU needed, 4/CU capacity
#define NLEAF  64            // barrier leaf lines (8 arrivals each)
#define BMW    4096          // bitmap words (2^17 bits); exact for N < 131072
#define MAXIT  4             // register-cached scan depth (covers E <= 2.09M)

// ws layout: hdr(256B) | bar(8448B: 64 leaf lines + gen line) | nodecnt(2048B)
// | partials | L2_src | L2_ea | buck(2MB) | xl2.  First 10752 B zeroed by
// hipMemsetAsync each call (ws re-poisoned to 0xAA between launches).
// All cross-phase data via agent-scope RELAXED atomics (sc1 -> LLC, bypassing
// non-coherent XCD L2s); barrier is fence-free: __syncthreads() drains vmcnt
// (all sc1 stores at LLC) before the arrival RMW.  (R7/R8, absmax 0.0)

__device__ __forceinline__ int aload_i(const int* p) {
    return __hip_atomic_load((int*)p, __ATOMIC_RELAXED, __HIP_MEMORY_SCOPE_AGENT);
}
__device__ __forceinline__ void astore_i(int* p, int v) {
    __hip_atomic_store(p, v, __ATOMIC_RELAXED, __HIP_MEMORY_SCOPE_AGENT);
}
__device__ __forceinline__ float aload_f(const float* p) {
    return __hip_atomic_load((float*)p, __ATOMIC_RELAXED, __HIP_MEMORY_SCOPE_AGENT);
}
__device__ __forceinline__ void astore_f(float* p, float v) {
    __hip_atomic_store(p, v, __ATOMIC_RELAXED, __HIP_MEMORY_SCOPE_AGENT);
}
__device__ __forceinline__ unsigned long long aload_u64(const unsigned long long* p) {
    return __hip_atomic_load((unsigned long long*)p, __ATOMIC_RELAXED, __HIP_MEMORY_SCOPE_AGENT);
}
__device__ __forceinline__ void astore_u64(unsigned long long* p, unsigned long long v) {
    __hip_atomic_store(p, v, __ATOMIC_RELAXED, __HIP_MEMORY_SCOPE_AGENT);
}

// Flat-fanout monotonic barrier: 64 leaf lines (8 serialized RMWs each, not
// 64 as in R8), block 0's wave 0 detects via one 64-lane parallel load +
// butterfly sum, then stores the generation. All RELAXED (no cache ops).
__device__ __forceinline__ void grid_sync(int* bar, int epoch) {
    __syncthreads();
    if (threadIdx.x < 64) {
        int lane = threadIdx.x;
        if (lane == 0)
            __hip_atomic_fetch_add(&bar[32 * (blockIdx.x & (NLEAF - 1))], 1,
                                   __ATOMIC_RELAXED, __HIP_MEMORY_SCOPE_AGENT);
        if (blockIdx.x == 0) {
            int target = (epoch + 1) * NBLK;
            for (;;) {
                int v = __hip_atomic_load(&bar[32 * lane], __ATOMIC_RELAXED,
                                          __HIP_MEMORY_SCOPE_AGENT);
                for (int o = 32; o >= 1; o >>= 1) v += __shfl_xor(v, o, 64);
                if (v >= target) break;
                __builtin_amdgcn_s_sleep(1);
            }
            if (lane == 0)
                __hip_atomic_store(&bar[32 * NLEAF], epoch + 1,
                                   __ATOMIC_RELAXED, __HIP_MEMORY_SCOPE_AGENT);
        } else if (lane == 0) {
            while (__hip_atomic_load(&bar[32 * NLEAF], __ATOMIC_RELAXED,
                                     __HIP_MEMORY_SCOPE_AGENT) < epoch + 1)
                __builtin_amdgcn_s_sleep(2);
        }
    }
    __syncthreads();
}

__global__ __launch_bounds__(256, 4)
void k_mega(const float* __restrict__ x, const int* __restrict__ ei,
            const float* __restrict__ ea, const int* __restrict__ tptr,
            const float* __restrict__ Wl1, const float* __restrict__ bl1,
            const float* __restrict__ Wr1, const float* __restrict__ br1,
            const float* __restrict__ We1, const float* __restrict__ att1,
            const float* __restrict__ b1,
            const float* __restrict__ Wl2, const float* __restrict__ bl2,
            const float* __restrict__ Wr2, const float* __restrict__ br2,
            const float* __restrict__ We2, const float* __restrict__ att2,
            const float* __restrict__ b2,
            const float* __restrict__ Wf, const float* __restrict__ bf,
            int E,
            int* hdr, int* bar, int* nodecnt, float* partials,
            int* L2_src, float* L2_ea,
            unsigned long long* buck,
            float* xl2, float* out) {
    int tid = threadIdx.x, lane = tid & 63, wq = tid >> 6;
    int bid = blockIdx.x;
    int gid = bid * 256 + tid;
    const int gstride = NBLK * 256;

    __shared__ float wsum[4];
    __shared__ int   s1[CAPS1];
    __shared__ int   l2idx[CAP2];
    __shared__ int   esrc[CAPN + 1];
    __shared__ float eea[CAPN + 1];
    __shared__ float xsA[CAPN + 1], xsB[CAPN + 1];
    __shared__ float scores[CAPN + 1];
    __shared__ float part[4][64];
    __shared__ float hrow[64];
    __shared__ float xr2s[64];
    __shared__ int   bitmap[BMW];      // phase 3; reused as xl2sh in phase 5
    __shared__ float m_sh, d_sh, eam_sh;
    __shared__ int   n_sh;

    const int4*   dst4 = (const int4*)(ei + E);
    const float4* ea4  = (const float4*)ea;
    int E4 = E >> 2;
    int t = tptr[0];

    // ---------------- phase 1: scanA, register-cached dst --------------------
    // all 2*MAXIT loads issued back-to-back (one exposed latency); rc[] kept
    // in VGPRs for phase 3 (no global dst reads there).
    int4   rc[MAXIT];
    float4 rea[MAXIT];
    #pragma unroll
    for (int i = 0; i < MAXIT; i++) {
        int e4 = gid + i * gstride;
        rc[i]  = (e4 < E4) ? dst4[e4] : make_int4(-1, -1, -1, -1);
        rea[i] = (e4 < E4) ? ea4[e4]  : make_float4(0.f, 0.f, 0.f, 0.f);
    }
    {
        float local = 0.f;
        #pragma unroll
        for (int i = 0; i < MAXIT; i++) {
            int e4 = gid + i * gstride;
            if (e4 < E4) {
                float4 a = rea[i];
                local += a.x + a.y + a.z + a.w;
                int4 d = rc[i];
                int eb = e4 * 4;
                if (d.x == t) { int p = atomicAdd(&hdr[0], 1); if (p < CAP2) { astore_i(&L2_src[p], ei[eb]);     astore_f(&L2_ea[p], a.x); } }
                if (d.y == t) { int p = atomicAdd(&hdr[0], 1); if (p < CAP2) { astore_i(&L2_src[p], ei[eb + 1]); astore_f(&L2_ea[p], a.y); } }
                if (d.z == t) { int p = atomicAdd(&hdr[0], 1); if (p < CAP2) { astore_i(&L2_src[p], ei[eb + 2]); astore_f(&L2_ea[p], a.z); } }
                if (d.w == t) { int p = atomicAdd(&hdr[0], 1); if (p < CAP2) { astore_i(&L2_src[p], ei[eb + 3]); astore_f(&L2_ea[p], a.w); } }
            }
        }
        // generic overflow (E4 > MAXIT*gstride) — empty at E=1.6M
        for (int e4 = gid + MAXIT * gstride; e4 < E4; e4 += gstride) {
            int4 d = dst4[e4];
            float4 a = ea4[e4];
            local += a.x + a.y + a.z + a.w;
            int eb = e4 * 4;
            if (d.x == t) { int p = atomicAdd(&hdr[0], 1); if (p < CAP2) { astore_i(&L2_src[p], ei[eb]);     astore_f(&L2_ea[p], a.x); } }
            if (d.y == t) { int p = atomicAdd(&hdr[0], 1); if (p < CAP2) { astore_i(&L2_src[p], ei[eb + 1]); astore_f(&L2_ea[p], a.y); } }
            if (d.z == t) { int p = atomicAdd(&hdr[0], 1); if (p < CAP2) { astore_i(&L2_src[p], ei[eb + 2]); astore_f(&L2_ea[p], a.z); } }
            if (d.w == t) { int p = atomicAdd(&hdr[0], 1); if (p < CAP2) { astore_i(&L2_src[p], ei[eb + 3]); astore_f(&L2_ea[p], a.w); } }
        }
        if (gid == 0) {                  // tail (E % 4)
            for (int e = E4 * 4; e < E; e++) {
                float a = ea[e];
                local += a;
                if (ei[E + e] == t) { int p = atomicAdd(&hdr[0], 1); if (p < CAP2) { astore_i(&L2_src[p], ei[e]); astore_f(&L2_ea[p], a); } }
            }
        }
        for (int o = 32; o >= 1; o >>= 1) local += __shfl_xor(local, o, 64);
        if (lane == 0) wsum[wq] = local;
        __syncthreads();
        if (tid == 0) astore_f(&partials[bid], wsum[0] + wsum[1] + wsum[2] + wsum[3]);
    }
    grid_sync(bar, 0);

    // ------- phase 2+3: ea_sum reduce, ballot dedupe, bitmap, scanC ---------
    int c2 = aload_i(&hdr[0]); if (c2 > CAP2) c2 = CAP2;
    {
        float local = aload_f(&partials[tid]) + aload_f(&partials[tid + 256]);
        for (int o = 32; o >= 1; o >>= 1) local += __shfl_xor(local, o, 64);
        if (lane == 0) wsum[wq] = local;
        __syncthreads();
        if (tid == 0) eam_sh = (wsum[0] + wsum[1] + wsum[2] + wsum[3]) / (float)E;

        if (wq == 0) {                    // dedupe (every block, redundantly)
            if (c2 <= 64) {
                int v = (lane < c2) ? aload_i(&L2_src[lane]) : -1;
                int first = lane;
                #pragma unroll
                for (int j = 0; j < 64; j++) {
                    int vj = __shfl(v, j);
                    if (j < first && vj == v) first = j;
                }
                bool isfirst = (lane < c2) && (first == lane) && (v != t);
                unsigned long long bfm = __ballot(isfirst);
                int myidx = (v == t) ? 0
                            : (1 + (int)__popcll(bfm & ((1ull << lane) - 1)));
                int idx = __shfl(myidx, first);
                if (lane < c2) l2idx[lane] = idx;
                if (isfirst) s1[myidx] = v;
                if (lane == 0) { s1[0] = t; n_sh = 1 + (int)__popcll(bfm); }
            } else if (lane == 0) {        // serial fallback
                s1[0] = t;
                int n = 1;
                for (int k = 0; k < c2; k++) {
                    int v = aload_i(&L2_src[k]);
                    int idx = -1;
                    for (int j = 0; j < n; j++) if (s1[j] == v) { idx = j; break; }
                    if (idx < 0) { idx = n; s1[n] = v; n++; }
                    l2idx[k] = idx;
                }
                n_sh = n;
            }
        }
        for (int w = tid; w < BMW; w += 256) bitmap[w] = 0;
        __syncthreads();
        int n_s1 = n_sh;
        for (int j = tid; j < n_s1; j += 256) {
            int u = s1[j];
            atomicOr(&bitmap[(u >> 5) & (BMW - 1)], 1 << (u & 31));
        }
        __syncthreads();

        // scanC over the register-cached dst: no global dst loads; src/ea
        // loaded only on a true hit (~300 grid-wide), pushed to per-node bucket.
        #pragma unroll
        for (int i = 0; i < MAXIT; i++) {
            int e4 = gid + i * gstride;
            if (e4 < E4) {
                int4 d = rc[i];
                int eb = e4 * 4;
                int dd[4] = {d.x, d.y, d.z, d.w};
                float av[4] = {rea[i].x, rea[i].y, rea[i].z, rea[i].w};
                #pragma unroll
                for (int q = 0; q < 4; q++) {
                    int dv = dd[q];
                    if (dv >= 0 && (bitmap[(dv >> 5) & (BMW - 1)] & (1 << (dv & 31)))) {
                        int idx = -1;
                        for (int j = 0; j < n_s1; j++) if (s1[j] == dv) { idx = j; break; }
                        if (idx >= 0) {
                            int slot = __hip_atomic_fetch_add(&nodecnt[idx], 1,
                                         __ATOMIC_RELAXED, __HIP_MEMORY_SCOPE_AGENT);
                            if (slot < CAPN) {
                                unsigned long long pk =
                                    ((unsigned long long)__float_as_uint(av[q]) << 32) |
                                    (unsigned)ei[eb + q];
                                astore_u64(&buck[(size_t)idx * CAPN + slot], pk);
                            }
                        }
                    }
                }
            }
        }
        for (int e4 = gid + MAXIT * gstride; e4 < E4; e4 += gstride) {
            int4 d = dst4[e4];
            int eb = e4 * 4;
            int dd[4] = {d.x, d.y, d.z, d.w};
            #pragma unroll
            for (int q = 0; q < 4; q++) {
                int dv = dd[q];
                if (bitmap[(dv >> 5) & (BMW - 1)] & (1 << (dv & 31))) {
                    int idx = -1;
                    for (int j = 0; j < n_s1; j++) if (s1[j] == dv) { idx = j; break; }
                    if (idx >= 0) {
                        int slot = __hip_atomic_fetch_add(&nodecnt[idx], 1,
                                     __ATOMIC_RELAXED, __HIP_MEMORY_SCOPE_AGENT);
                        if (slot < CAPN) {
                            unsigned long long pk =
                                ((unsigned long long)__float_as_uint(ea[eb + q]) << 32) |
                                (unsigned)ei[eb + q];
                            astore_u64(&buck[(size_t)idx * CAPN + slot], pk);
                        }
                    }
                }
            }
        }
        if (gid == 0) {
            for (int e = E4 * 4; e < E; e++) {
                int dv = ei[E + e];
                int idx = -1;
                for (int j = 0; j < n_s1; j++) if (s1[j] == dv) { idx = j; break; }
                if (idx >= 0) {
                    int slot = __hip_atomic_fetch_add(&nodecnt[idx], 1,
                                 __ATOMIC_RELAXED, __HIP_MEMORY_SCOPE_AGENT);
                    if (slot < CAPN) {
                        unsigned long long pk =
                            ((unsigned long long)__float_as_uint(ea[e]) << 32) |
                            (unsigned)ei[e];
                        astore_u64(&buck[(size_t)idx * CAPN + slot], pk);
                    }
                }
            }
        }
    }
    grid_sync(bar, 1);

    int n_s1 = n_sh;
    float eam = eam_sh;

    // ---------------- phase 4: layer 1 + fused layer-2 transforms -----------
    for (int node = bid; node < n_s1; node += NBLK) {
        int v = s1[node];
        int cnt = aload_i(&nodecnt[node]); if (cnt > CAPN) cnt = CAPN;
        for (int k = tid; k < cnt; k += 256) {        // own bucket only
            unsigned long long pk = aload_u64(&buck[(size_t)node * CAPN + k]);
            esrc[k] = (int)(unsigned)(pk & 0xffffffffull);
            eea[k]  = __uint_as_float((unsigned)(pk >> 32));
        }
        __syncthreads();
        int nE = cnt;
        if (tid == 0) { esrc[nE] = v; eea[nE] = eam; }   // self-loop
        __syncthreads();
        nE += 1;

        const float2* x2 = (const float2*)x;
        for (int j = tid; j < nE; j += 256) {            // parallel x gather
            float2 xv = x2[esrc[j]];
            xsA[j] = xv.x; xsB[j] = xv.y;
        }
        __syncthreads();

        float wl0 = Wl1[lane], wl1w = Wl1[64 + lane], bl = bl1[lane];
        float we = We1[lane], at = att1[lane];
        float2 xv = x2[v];
        float xr = xv.x * Wr1[lane] + xv.y * Wr1[64 + lane] + br1[lane];

        for (int k = wq; k < nE; k += 4) {               // scores
            float xl = xsA[k] * wl0 + xsB[k] * wl1w + bl;
            float ev = xl + xr + eea[k] * we;
            ev = ev > 0.f ? ev : 0.2f * ev;
            float p = ev * at;
            for (int o = 32; o >= 1; o >>= 1) p += __shfl_xor(p, o, 64);
            if (lane == 0) scores[k] = p;
        }
        __syncthreads();

        if (wq == 0) {                                   // softmax stats
            float m = -3.4e38f;
            for (int k = lane; k < nE; k += 64) m = fmaxf(m, scores[k]);
            for (int o = 32; o >= 1; o >>= 1) m = fmaxf(m, __shfl_xor(m, o, 64));
            float d = 0.f;
            for (int k = lane; k < nE; k += 64) d += expf(scores[k] - m);
            for (int o = 32; o >= 1; o >>= 1) d += __shfl_xor(d, o, 64);
            if (lane == 0) { m_sh = m; d_sh = d; }
        }
        __syncthreads();
        float m = m_sh, dinv = 1.f / d_sh;

        float acc = 0.f;                                 // weighted sum
        for (int k = wq; k < nE; k += 4) {
            float xl = xsA[k] * wl0 + xsB[k] * wl1w + bl;
            acc += expf(scores[k] - m) * dinv * xl;
        }
        part[wq][lane] = acc;
        __syncthreads();
        if (tid < 64) {
            float h = part[0][lane] + part[1][lane] + part[2][lane] + part[3][lane] + b1[lane];
            hrow[lane] = h > 0.f ? h : 0.f;
        }
        __syncthreads();

        // fused: xl2[node] = Wl2^T hrow + bl2 (k-split across waves)
        float p = 0.f;
        int k0 = 16 * wq;
        for (int k = k0; k < k0 + 16; k++) p += hrow[k] * Wl2[k * 64 + lane];
        part[wq][lane] = p;
        __syncthreads();
        if (tid < 64)
            astore_f(&xl2[node * 64 + lane],
                     part[0][lane] + part[1][lane] + part[2][lane] + part[3][lane] + bl2[lane]);

        if (node == 0) {                                 // target transform -> LDS
            __syncthreads();
            float p2 = 0.f;
            for (int k = k0; k < k0 + 16; k++) p2 += hrow[k] * Wr2[k * 64 + lane];
            part[wq][lane] = p2;
            __syncthreads();
            if (tid < 64)
                xr2s[lane] = part[0][lane] + part[1][lane] + part[2][lane] + part[3][lane] + br2[lane];
        }
        __syncthreads();
    }
    grid_sync(bar, 2);

    // -------- phase 5 (block 0, all 4 waves): layer-2 softmax + head --------
    if (bid == 0) {
        int nE2 = c2;
        float* xl2sh = (float*)bitmap;                   // reuse 16 KB
        int rows = n_s1 < 64 ? n_s1 : 64;
        for (int i = tid; i < rows * 64; i += 256) xl2sh[i] = aload_f(&xl2[i]);
        for (int j = tid; j < nE2; j += 256) eea[j] = aload_f(&L2_ea[j]);
        __syncthreads();

        float we = We2[lane], at = att2[lane], xr = xr2s[lane];
        for (int j = wq; j <= nE2; j += 4) {             // scores over waves
            int   idx = (j < nE2) ? l2idx[j] : 0;
            float eav = (j < nE2) ? eea[j]   : eam;
            float xlv = (idx < 64) ? xl2sh[idx * 64 + lane]
                                   : aload_f(&xl2[idx * 64 + lane]);
            float ev = xlv + xr + eav * we;
            ev = ev > 0.f ? ev : 0.2f * ev;
            float p = ev * at;
            for (int o = 32; o >= 1; o >>= 1) p += __shfl_xor(p, o, 64);
            if (lane == 0) scores[j] = p;
        }
        __syncthreads();

        if (wq == 0) {                                   // softmax stats
            int tot = nE2 + 1;
            float m = -3.4e38f;
            for (int j = lane; j < tot; j += 64) m = fmaxf(m, scores[j]);
            for (int o = 32; o >= 1; o >>= 1) m = fmaxf(m, __shfl_xor(m, o, 64));
            float d = 0.f;
            for (int j = lane; j < tot; j += 64) d += expf(scores[j] - m);
            for (int o = 32; o >= 1; o >>= 1) d += __shfl_xor(d, o, 64);
            if (lane == 0) { m_sh = m; d_sh = d; }
        }
        __syncthreads();
        float m = m_sh, dinv = 1.f / d_sh;

        float acc = 0.f;                                 // weighted sum over waves
        for (int j = wq; j <= nE2; j += 4) {
            int idx = (j < nE2) ? l2idx[j] : 0;
            float xlv = (idx < 64) ? xl2sh[idx * 64 + lane]
                                   : aload_f(&xl2[idx * 64 + lane]);
            acc += expf(scores[j] - m) * dinv * xlv;
        }
        part[wq][lane] = acc;
        __syncthreads();
        if (tid < 64) {
            float h = part[0][lane] + part[1][lane] + part[2][lane] + part[3][lane] + b2[lane];
            hrow[lane] = h > 0.f ? h : 0.f;
        }
        __syncthreads();
        if (tid < 128) {                                 // head: [64]@[64,128]+bf
            float r = bf[tid];
            for (int c = 0; c < 64; c++) r += hrow[c] * Wf[c * 128 + tid];
            out[tid] = r;
        }
    }
}

extern "C" void kernel_launch(void* const* d_in, const int* in_sizes, int n_in,
                              void* d_out, int out_size, void* d_ws, size_t ws_size,
                              hipStream_t stream) {
    const float* x    = (const float*)d_in[0];
    const int*   ei   = (const int*)  d_in[1];
    const float* ea   = (const float*)d_in[2];
    const int*   tptr = (const int*)  d_in[3];
    const float* Wl1  = (const float*)d_in[4];
    const float* bl1  = (const float*)d_in[5];
    const float* Wr1  = (const float*)d_in[6];
    const float* br1  = (const float*)d_in[7];
    const float* We1  = (const float*)d_in[8];
    const float* att1 = (const float*)d_in[9];
    const float* b1   = (const float*)d_in[10];
    const float* Wl2  = (const float*)d_in[11];
    const float* bl2  = (const float*)d_in[12];
    const float* Wr2  = (const float*)d_in[13];
    const float* br2  = (const float*)d_in[14];
    const float* We2  = (const float*)d_in[15];
    const float* att2 = (const float*)d_in[16];
    const float* b2   = (const float*)d_in[17];
    const float* Wf   = (const float*)d_in[18];
    const float* bf   = (const float*)d_in[19];

    int E = in_sizes[2];

    char* base = (char*)d_ws;
    int*   hdr      = (int*)base;   base += 256;
    int*   bar      = (int*)base;   base += 8448;   // 64 leaf lines + gen line
    int*   nodecnt  = (int*)base;   base += 2048;   // per-node bucket counters
    float* partials = (float*)base; base += NBLK * sizeof(float);
    int*   L2_src   = (int*)base;   base += 512 * sizeof(int);
    float* L2_ea    = (float*)base; base += 512 * sizeof(float);
    unsigned long long* buck = (unsigned long long*)base;
    base += (size_t)CAPS1 * CAPN * sizeof(unsigned long long);   // 2 MB
    float* xl2      = (float*)base; base += (size_t)CAPS1 * 64 * sizeof(float);

    // Load-bearing: ws re-poisoned to 0xAA before every timed launch;
    // hdr + barrier epochs + bucket counters must start at 0.
    hipMemsetAsync(hdr, 0, 256 + 8448 + 2048, stream);

    hipLaunchKernelGGL(k_mega, dim3(NBLK), dim3(256), 0, stream,
                       x, ei, ea, tptr,
                       Wl1, bl1, Wr1, br1, We1, att1, b1,
                       Wl2, bl2, Wr2, br2, We2, att2, b2,
                       Wf, bf, E,
                       hdr, bar, nodecnt, partials,
                       L2_src, L2_ea,
                       buck, xl2, (float*)d_out);
}